// Round 2
// baseline (749.880 us; speedup 1.0000x reference)
//
#include <hip/hip_runtime.h>

// Problem constants (fixed by setup_inputs)
#define BB 4
#define CC 64      // feature channels
#define KK 16      // neighbors
#define NN 16384   // points
#define NTB 64     // points per block = one 64-pt group, 4 waves

typedef __attribute__((ext_vector_type(8))) short short8;     // 8 bf16 (MFMA A/B)
typedef __attribute__((ext_vector_type(4))) float floatx4;    // MFMA C/D
typedef __attribute__((ext_vector_type(2))) _Float16 half2v;  // packed f16 pair

__device__ __forceinline__ unsigned short f2bf_rtne(float x) {  // RTNE f32->bf16
    unsigned u = __builtin_bit_cast(unsigned, x);
    u += 0x7FFFu + ((u >> 16) & 1u);
    return (unsigned short)(u >> 16);
}

// pack two f32 into bf16x2 (round-half-up via +0x8000, then v_perm byte-select)
__device__ __forceinline__ unsigned pack_bf16x2(float lo, float hi) {
    unsigned a = __builtin_bit_cast(unsigned, lo) + 0x8000u;
    unsigned b = __builtin_bit_cast(unsigned, hi) + 0x8000u;
    return __builtin_amdgcn_perm(b, a, 0x07060302u);  // {b.hi16, a.hi16}
}

// cvt_pkrtz returns __fp16x2; bit_cast to _Float16x2 for fdot2
__device__ __forceinline__ half2v cvt2h(float a, float b) {
    return __builtin_bit_cast(half2v, __builtin_amdgcn_cvt_pkrtz(a, b));
}

#if __has_builtin(__builtin_amdgcn_fdot2)
#define DOT2(a, b, c) __builtin_amdgcn_fdot2((a), (b), (c), false)
#else
__device__ __forceinline__ float dot2_fb(half2v a, half2v b, float c) {
    return fmaf((float)a[0], (float)b[0], fmaf((float)a[1], (float)b[1], c));
}
#define DOT2(a, b, c) dot2_fb((a), (b), (c))
#endif

// ---------------------------------------------------------------------------
// One-time: repack lin_w (f32 [64][1024]) into bf16 MFMA B-fragments in the
// exact per-wave load order: [chunk ci][kk][nt][lane]{8 bf16}. 128 KB, L2-hot.
// Also zeroes the BN partial-sum buffer (fused_main accumulates via atomics).
// ---------------------------------------------------------------------------
__global__ __launch_bounds__(256)
void prep_bfrag(const float* __restrict__ lin_w, unsigned short* __restrict__ bfrag,
                float* __restrict__ part)
{
    const int tid  = blockIdx.x * 256 + threadIdx.x;  // 0..8191
    if (tid < 512) part[tid] = 0.0f;                  // BN sum/sumsq partials

    const int lane = tid & 63;
    const int g    = tid >> 6;            // 0..127 = (ci,kk,nt)
    const int ci   = g >> 4;
    const int kk   = (g >> 2) & 3;
    const int nt   = g & 3;
    const int r    = lane & 15;
    const int sq   = lane >> 4;

    const float* src = lin_w + (size_t)(nt * 16 + r) * 1024 + ci * 128 + kk * 32 + sq * 8;
    unsigned short v[8];
    #pragma unroll
    for (int j = 0; j < 8; ++j) v[j] = f2bf_rtne(src[j]);
    *(uint4*)(bfrag + ((size_t)g * 64 + lane) * 8) = *(const uint4*)v;
}

// ---------------------------------------------------------------------------
// Fused weightnet + aggregation + linear(MFMA) + BN partial reduction.
//
// NEW decomposition this round (occupancy attack): block = 4 waves over ONE
// 64-point group. Wave w computes weightnet/agg for o in [4w,4w+4) (wh 32
// regs, was 64) and owns output M-tile Mt=w (acc 16 regs, was 32). points
// values are packed to f16 pairs on arrival (pv 32 regs, was 64). Steady
// state ~145 VGPR -> __launch_bounds__(256,3) = 12 waves/CU (was 8), 1.5x
// latency tolerance. Block-level points read redundancy is 4x (was 2x) but
// L1/L2-absorbed; HBM fetch unchanged (~268 MB).
//
// s_a is A-FRAGMENT-NATIVE [Mt][kk][r][sq] (uint4, Mt stride 257), double
// buffered; cross-barrier pipeline retained: region ci runs channel(ci+1)
// then MFMA(ci); one lgkm-only barrier per region (vmcnt never drained, so
// pv refills + B-frag loads stay in flight across barriers).
// k' = cc*16 + o: wave w's 4 o's land in dword pair (w&1)*2 of sq-slot
// (cl&1)*2 + (w>>1)  ->  ds_write_b64, two waves fill each uint4 disjointly.
//
// Epilogue: per-wave shuffle-reduce of sum/sumsq over sq -> 8 atomicAdds per
// wave into part[] (bn_reduce kernel deleted; saves a 17 MB re-read).
// lin_b dropped: training-mode BN cancels per-channel shifts.
// ---------------------------------------------------------------------------
__global__ __launch_bounds__(256, 3)
void fused_main(const float* __restrict__ points,
                const float* __restrict__ coordinate,
                const float* __restrict__ w1,
                const float* __restrict__ b1,
                const unsigned short* __restrict__ bfrag,
                float* __restrict__ y_out,    // [B][C][N] pre-BN
                float* __restrict__ part)     // [2][B][64] sums/sumsq
{
    __shared__ uint4 s_a[2][4 * 257];  // [buf][Mt*257 + kk*64 + r*4 + sq]

    const int t    = threadIdx.x;
    const int lane = t & 63;
    const int w    = __builtin_amdgcn_readfirstlane(t >> 6);  // wave 0..3
    const int r    = lane & 15;
    const int sq   = lane >> 4;

    const int bid = blockIdx.x;
    const int b   = bid >> 8;            // 256 blocks per batch
    const int n0  = (bid & 255) * NTB;   // group's point base in batch

    // ---- weightnet into f16-pair registers: wh[j][kp], o = 4w + j
    half2v wh[4][8];
    {
        const float* coordB = coordinate + (size_t)b * 3 * KK * NN + n0 + lane;
        float c0[KK], c1[KK], c2[KK];
        #pragma unroll
        for (int k = 0; k < KK; ++k) {
            c0[k] = coordB[(0 * KK + k) * NN];
            c1[k] = coordB[(1 * KK + k) * NN];
            c2[k] = coordB[(2 * KK + k) * NN];
        }
        #pragma unroll
        for (int j = 0; j < 4; ++j) {
            const int o = 4 * w + j;
            const float w1x = w1[o * 3 + 0];
            const float w1y = w1[o * 3 + 1];
            const float w1z = w1[o * 3 + 2];
            const float bo  = b1[o];
            #pragma unroll
            for (int kp = 0; kp < 8; ++kp) {
                float v0 = fmaf(w1x, c0[2 * kp],     fmaf(w1y, c1[2 * kp],     fmaf(w1z, c2[2 * kp],     bo)));
                float v1 = fmaf(w1x, c0[2 * kp + 1], fmaf(w1y, c1[2 * kp + 1], fmaf(w1z, c2[2 * kp + 1], bo)));
                wh[j][kp] = cvt2h(fmaxf(v0, 0.0f), fmaxf(v1, 0.0f));
            }
        }
    }

    floatx4 acc[4];
    #pragma unroll
    for (int nt = 0; nt < 4; ++nt) acc[nt] = (floatx4){0.f, 0.f, 0.f, 0.f};

    const float* pB = points + (size_t)b * CC * KK * NN + n0 + lane;  // lane's column

    // ---- prime the distance-4 points pipeline (channels 0..3), packed f16
    half2v pv[4][8];
    #pragma unroll
    for (int d = 0; d < 4; ++d)
        #pragma unroll
        for (int i = 0; i < 8; ++i)
            pv[d][i] = cvt2h(pB[((size_t)(d * KK + 2 * i))     * NN],
                             pB[((size_t)(d * KK + 2 * i + 1)) * NN]);

    // ---- channel section for chunk c_: consumes pv, refills, writes s_a[c_&1]
#define CHANNEL_SECTION(CARG)                                                   \
    {                                                                           \
        const int c_ = (CARG);                                                  \
        uint4* saW = &s_a[c_ & 1][0];                                           \
        _Pragma("unroll")                                                       \
        for (int cl = 0; cl < 8; ++cl) {                                        \
            const int cc   = c_ * 8 + cl;                                       \
            const int slot = cl & 3;        /* (c_*8+cl)&3 == cl&3 */           \
            float a8[4];                                                        \
            _Pragma("unroll")                                                   \
            for (int j = 0; j < 4; ++j) {                                       \
                float a = 0.f;                                                  \
                _Pragma("unroll")                                               \
                for (int kp = 0; kp < 8; ++kp) a = DOT2(pv[slot][kp], wh[j][kp], a); \
                a8[j] = a;                                                      \
            }                                                                   \
            {                                                                   \
                const int cp = (cc + 4 < CC) ? (cc + 4) : (CC - 1);             \
                _Pragma("unroll")                                               \
                for (int i = 0; i < 8; ++i)                                     \
                    pv[slot][i] = cvt2h(pB[((size_t)(cp * KK + 2 * i))     * NN], \
                                        pB[((size_t)(cp * KK + 2 * i + 1)) * NN]); \
            }                                                                   \
            uint2 pk;                                                           \
            pk.x = pack_bf16x2(a8[0], a8[1]);                                   \
            pk.y = pack_bf16x2(a8[2], a8[3]);                                   \
            uint2* dst = (uint2*)&saW[(lane >> 4) * 257 + (cl >> 1) * 64        \
                                      + (lane & 15) * 4 + (cl & 1) * 2          \
                                      + (w >> 1)] + (w & 1);                    \
            *dst = pk;                                                          \
        }                                                                       \
    }

    // ---- prologue region: channel(0), B-frags (0,kk=0), barrier
    CHANNEL_SECTION(0)

    uint4 bf_c[4];
    #pragma unroll
    for (int nt = 0; nt < 4; ++nt)
        bf_c[nt] = *(const uint4*)(bfrag + ((((size_t)0 * 4 + 0) * 4 + nt) * 64 + lane) * 8);

    // LDS-only barrier: lgkmcnt(0) for s_a visibility, NO vmcnt drain
    asm volatile("s_waitcnt lgkmcnt(0)\n\ts_barrier" ::: "memory");

    for (int ci = 0; ci < 8; ++ci) {
        // 1) next chunk's channel work first (writes buf (ci+1)&1); bf_c for
        //    THIS chunk stays in flight underneath.
        if (ci < 7) CHANNEL_SECTION(ci + 1)

        // 2) MFMA for chunk ci from s_a[ci&1]; wave w consumes only Mt=w.
        const uint4* saR = &s_a[ci & 1][0];
        #pragma unroll
        for (int kk = 0; kk < 4; ++kk) {
            uint4 bf_n[4];
            if (kk < 3) {
                #pragma unroll
                for (int nt = 0; nt < 4; ++nt)
                    bf_n[nt] = *(const uint4*)(bfrag + ((((size_t)ci * 4 + kk + 1) * 4 + nt) * 64 + lane) * 8);
            }
            const short8 af = __builtin_bit_cast(short8, saR[w * 257 + kk * 64 + r * 4 + sq]);
            #pragma unroll
            for (int nt = 0; nt < 4; ++nt)
                acc[nt] = __builtin_amdgcn_mfma_f32_16x16x32_bf16(
                    af, __builtin_bit_cast(short8, bf_c[nt]), acc[nt], 0, 0, 0);
            #pragma unroll
            for (int nt = 0; nt < 4; ++nt) bf_c[nt] = bf_n[nt];
        }

        // 3) pre-issue next chunk's kk=0 B-frags, then lgkm-only barrier.
        if (ci < 7) {
            #pragma unroll
            for (int nt = 0; nt < 4; ++nt)
                bf_c[nt] = *(const uint4*)(bfrag + ((((size_t)(ci + 1) * 4 + 0) * 4 + nt) * 64 + lane) * 8);
            asm volatile("s_waitcnt lgkmcnt(0)\n\ts_barrier" ::: "memory");
        }
    }
#undef CHANNEL_SECTION

    // ---- epilogue: store y + BN partial sums.
    // D: col=lane&15 (oc), row=sq*4+reg (point within wave's 16-pt tile Mt=w)
    float* yB = y_out + (size_t)b * CC * NN + n0;
    #pragma unroll
    for (int nt = 0; nt < 4; ++nt) {
        const int oc = nt * 16 + r;
        const float4 v = make_float4(acc[nt][0], acc[nt][1], acc[nt][2], acc[nt][3]);
        *(float4*)(yB + (size_t)oc * NN + w * 16 + sq * 4) = v;

        float s  = v.x + v.y + v.z + v.w;
        float ss = v.x * v.x + v.y * v.y + v.z * v.z + v.w * v.w;
        s  += __shfl_xor(s, 16);  s  += __shfl_xor(s, 32);
        ss += __shfl_xor(ss, 16); ss += __shfl_xor(ss, 32);
        if (lane < 16) {  // lanes r==oc%16, sq==0: one add per (b,oc)
            atomicAdd(&part[b * 64 + oc], s);
            atomicAdd(&part[256 + b * 64 + oc], ss);
        }
    }
}

__global__ void bn_stats(const float* __restrict__ part,
                         const float* __restrict__ gamma,
                         const float* __restrict__ beta,
                         float* __restrict__ ab)
{
    const int ch = threadIdx.x;
    float S = 0.f, SS = 0.f;
    #pragma unroll
    for (int b = 0; b < BB; ++b) {
        S  += part[b * 64 + ch];
        SS += part[256 + b * 64 + ch];
    }
    const float inv  = 1.0f / (float)(BB * NN);
    const float mean = S * inv;
    const float var  = SS * inv - mean * mean;
    const float a    = gamma[ch] * rsqrtf(var + 1e-5f);
    ab[ch]      = a;
    ab[CC + ch] = beta[ch] - mean * a;
}

__global__ __launch_bounds__(256)
void bn_apply(float* __restrict__ y, const float* __restrict__ ab)
{
    const size_t i = (size_t)blockIdx.x * 256 + threadIdx.x;  // float4 index
    float4* p = (float4*)y;
    float4 v = p[i];
    const int ch = (int)((i * 4) >> 14) & 63;  // (elem / N) % C
    const float a = ab[ch], bb = ab[CC + ch];
    v.x = fmaxf(fmaf(a, v.x, bb), 0.0f);
    v.y = fmaxf(fmaf(a, v.y, bb), 0.0f);
    v.z = fmaxf(fmaf(a, v.z, bb), 0.0f);
    v.w = fmaxf(fmaf(a, v.w, bb), 0.0f);
    p[i] = v;
}

extern "C" void kernel_launch(void* const* d_in, const int* in_sizes, int n_in,
                              void* d_out, int out_size, void* d_ws, size_t ws_size,
                              hipStream_t stream)
{
    const float* xyz        = (const float*)d_in[0];
    const float* points     = (const float*)d_in[1];
    const float* coordinate = (const float*)d_in[2];
    const float* w1         = (const float*)d_in[3];
    const float* b1         = (const float*)d_in[4];
    const float* lin_w      = (const float*)d_in[5];
    // d_in[6] = lin_b: unused — training-mode BN cancels per-channel shifts
    const float* gamma      = (const float*)d_in[7];
    const float* beta       = (const float*)d_in[8];

    float* out = (float*)d_out;

    // workspace: [0,128K) bfrag bf16; then 512 floats partials; then 128 ab
    unsigned short* bfrag = (unsigned short*)d_ws;
    float* part = (float*)d_ws + 32768;
    float* ab   = part + 512;

    const size_t xyz_elems = (size_t)BB * NN * 3;  // output 0 passthrough
    (void)hipMemcpyAsync(out, xyz, xyz_elems * sizeof(float),
                         hipMemcpyDeviceToDevice, stream);

    float* y_out = out + xyz_elems;  // [B][C][N]

    prep_bfrag<<<32, 256, 0, stream>>>(lin_w, bfrag, part);
    fused_main<<<BB * (NN / NTB), 256, 0, stream>>>(
        points, coordinate, w1, b1, bfrag, y_out, part);
    bn_stats<<<1, 64, 0, stream>>>(part, gamma, beta, ab);
    bn_apply<<<(BB * CC * NN) / 4 / 256, 256, 0, stream>>>(y_out, ab);
}

// Round 3
// 400.461 us; speedup vs baseline: 1.8725x; 1.8725x over previous
//
#include <hip/hip_runtime.h>

// Problem constants (fixed by setup_inputs)
#define BB 4
#define CC 64      // feature channels
#define KK 16      // neighbors
#define NN 16384   // points
#define NTB 128    // points per block = 2 independent 64-point pairs

typedef __attribute__((ext_vector_type(8))) short short8;     // 8 bf16 (MFMA A/B)
typedef __attribute__((ext_vector_type(4))) float floatx4;    // MFMA C/D
typedef __attribute__((ext_vector_type(2))) _Float16 half2v;  // packed f16 pair

__device__ __forceinline__ unsigned short f2bf_rtne(float x) {  // RTNE f32->bf16
    unsigned u = __builtin_bit_cast(unsigned, x);
    u += 0x7FFFu + ((u >> 16) & 1u);
    return (unsigned short)(u >> 16);
}

// pack two f32 into bf16x2 (round-half-up via +0x8000, then v_perm byte-select)
__device__ __forceinline__ unsigned pack_bf16x2(float lo, float hi) {
    unsigned a = __builtin_bit_cast(unsigned, lo) + 0x8000u;
    unsigned b = __builtin_bit_cast(unsigned, hi) + 0x8000u;
    return __builtin_amdgcn_perm(b, a, 0x07060302u);  // {b.hi16, a.hi16}
}

// cvt_pkrtz returns __fp16x2; bit_cast to _Float16x2 for fdot2
__device__ __forceinline__ half2v cvt2h(float a, float b) {
    return __builtin_bit_cast(half2v, __builtin_amdgcn_cvt_pkrtz(a, b));
}

#if __has_builtin(__builtin_amdgcn_fdot2)
#define DOT2(a, b, c) __builtin_amdgcn_fdot2((a), (b), (c), false)
#else
__device__ __forceinline__ float dot2_fb(half2v a, half2v b, float c) {
    return fmaf((float)a[0], (float)b[0], fmaf((float)a[1], (float)b[1], c));
}
#define DOT2(a, b, c) dot2_fb((a), (b), (c))
#endif

// ---------------------------------------------------------------------------
// One-time: repack lin_w (f32 [64][1024]) into bf16 MFMA B-fragments in the
// exact per-wave load order: [chunk ci][kk][nt][lane]{8 bf16}. 128 KB, L2-hot.
// Also zeroes the BN partial-sum buffer (fused_main accumulates via atomics).
// ---------------------------------------------------------------------------
__global__ __launch_bounds__(256)
void prep_bfrag(const float* __restrict__ lin_w, unsigned short* __restrict__ bfrag,
                float* __restrict__ part)
{
    const int tid  = blockIdx.x * 256 + threadIdx.x;  // 0..8191
    if (tid < 512) part[tid] = 0.0f;                  // BN sum/sumsq partials

    const int lane = tid & 63;
    const int g    = tid >> 6;            // 0..127 = (ci,kk,nt)
    const int ci   = g >> 4;
    const int kk   = (g >> 2) & 3;
    const int nt   = g & 3;
    const int r    = lane & 15;
    const int sq   = lane >> 4;

    const float* src = lin_w + (size_t)(nt * 16 + r) * 1024 + ci * 128 + kk * 32 + sq * 8;
    unsigned short v[8];
    #pragma unroll
    for (int j = 0; j < 8; ++j) v[j] = f2bf_rtne(src[j]);
    *(uint4*)(bfrag + ((size_t)g * 64 + lane) * 8) = *(const uint4*)v;
}

// ---------------------------------------------------------------------------
// Fused weightnet + aggregation + linear(MFMA) + BN partial reduction.
// Block = 256 thr = 4 waves = 2 independent 64-point PAIRS.
// Pair P = waves {2P, 2P+1}; within a pair, wave h computes weightnet/agg for
// o in [8h, 8h+8) (2x read redundancy instead of round-4's 4x).
// s_a holds agg in A-FRAGMENT-NATIVE layout [Mt][kk][r][sq] (uint4 chunks,
// Mt stride 257 = 256+1 pad -> both ds_write_b128 and ds_read_b128 spread
// 8 lanes per 4-bank group = conflict-free). Double-buffered per pair so the
// chunk loop needs ONE barrier, emitted as raw lgkmcnt(0)+s_barrier: vmcnt
// is NOT drained, so the distance-4 points prefetch pipeline and pre-barrier
// B-fragment loads stay in flight across barriers.
// lin_b dropped: training-mode BN cancels per-channel shifts.
//
// ROUND-3 NOTE: this is the verified-best round-0 structure (407.5 us)
// reverted exactly — round-2's occupancy attack (launch_bounds(256,3)) left
// only 68 arch VGPRs (AGPR shuffle + L2 scratch, invisible in FETCH_SIZE)
// and its cvt-at-refill broke the prefetch pipeline: fused went 140->477 us.
// Only NEW change: BN partial reduction fused into the epilogue (bn_reduce
// kernel deleted; saves its 17 MB re-read + launch).
// ---------------------------------------------------------------------------
__global__ __launch_bounds__(256, 2)
void fused_main(const float* __restrict__ points,
                const float* __restrict__ coordinate,
                const float* __restrict__ w1,
                const float* __restrict__ b1,
                const unsigned short* __restrict__ bfrag,
                float* __restrict__ y_out,    // [B][C][N] pre-BN
                float* __restrict__ part)     // [2][B][64] sums / sumsq
{
    __shared__ uint4 s_a[2][2][4 * 257];  // [pair][buf][Mt*257 + kk*64 + r*4 + sq]

    const int t    = threadIdx.x;
    const int lane = t & 63;
    const int wv   = __builtin_amdgcn_readfirstlane(t >> 6);
    const int P    = wv >> 1;      // pair id
    const int h    = wv & 1;       // o-half within pair
    const int r    = lane & 15;
    const int sq   = lane >> 4;

    const int bid = blockIdx.x;
    const int b   = bid >> 7;                    // 128 blocks per batch
    const int n0  = (bid & 127) * NTB + P * 64;  // pair's point base in batch

    // ---- weightnet into f16-pair registers: wh[j][kp], o = 8h + j
    half2v wh[8][8];
    {
        const float* coordB = coordinate + (size_t)b * 3 * KK * NN + n0 + lane;
        float c0[KK], c1[KK], c2[KK];
        #pragma unroll
        for (int k = 0; k < KK; ++k) {
            c0[k] = coordB[(0 * KK + k) * NN];
            c1[k] = coordB[(1 * KK + k) * NN];
            c2[k] = coordB[(2 * KK + k) * NN];
        }
        #pragma unroll
        for (int j = 0; j < 8; ++j) {
            const int o = 8 * h + j;
            const float w1x = w1[o * 3 + 0];
            const float w1y = w1[o * 3 + 1];
            const float w1z = w1[o * 3 + 2];
            const float bo  = b1[o];
            #pragma unroll
            for (int kp = 0; kp < 8; ++kp) {
                float v0 = fmaf(w1x, c0[2 * kp],     fmaf(w1y, c1[2 * kp],     fmaf(w1z, c2[2 * kp],     bo)));
                float v1 = fmaf(w1x, c0[2 * kp + 1], fmaf(w1y, c1[2 * kp + 1], fmaf(w1z, c2[2 * kp + 1], bo)));
                wh[j][kp] = cvt2h(fmaxf(v0, 0.0f), fmaxf(v1, 0.0f));
            }
        }
    }

    floatx4 acc[2][4];
    #pragma unroll
    for (int m = 0; m < 2; ++m)
        #pragma unroll
        for (int nt = 0; nt < 4; ++nt) acc[m][nt] = (floatx4){0.f, 0.f, 0.f, 0.f};

    const float* pB = points + (size_t)b * CC * KK * NN + n0 + lane;  // lane's column

    // ---- prime the distance-4 points pipeline (channels 0..3), raw f32
    float pv[4][16];
    #pragma unroll
    for (int d = 0; d < 4; ++d)
        #pragma unroll
        for (int k = 0; k < KK; ++k)
            pv[d][k] = pB[((size_t)d * KK + k) * NN];

    for (int ci = 0; ci < 8; ++ci) {
        const int buf = ci & 1;
        uint4* saW = &s_a[P][buf][0];
        #pragma unroll
        for (int cl = 0; cl < 8; ++cl) {
            const int cc   = ci * 8 + cl;
            const int slot = cc & 3;
            // consume slot -> packed f16 (convert at CONSUME, not refill)
            half2v ph[8];
            #pragma unroll
            for (int kp = 0; kp < 8; ++kp)
                ph[kp] = cvt2h(pv[slot][2 * kp], pv[slot][2 * kp + 1]);
            // refill slot with channel cc+4 (clamped; tail loads are dead)
            {
                const int cp = (cc + 4 < CC) ? (cc + 4) : (CC - 1);
                #pragma unroll
                for (int k = 0; k < KK; ++k)
                    pv[slot][k] = pB[((size_t)cp * KK + k) * NN];
            }
            // 8-o dot over 16 k
            float a8[8];
            #pragma unroll
            for (int j = 0; j < 8; ++j) {
                float a = 0.f;
                #pragma unroll
                for (int kp = 0; kp < 8; ++kp) a = DOT2(ph[kp], wh[j][kp], a);
                a8[j] = a;
            }
            uint4 pk;
            pk.x = pack_bf16x2(a8[0], a8[1]);
            pk.y = pack_bf16x2(a8[2], a8[3]);
            pk.z = pack_bf16x2(a8[4], a8[5]);
            pk.w = pack_bf16x2(a8[6], a8[7]);
            // A-frag-native store: n=lane -> Mt=lane>>4, r=lane&15;
            // k' = cl*16+8h -> kk=cl>>1, sq=(cl&1)*2+h
            saW[(lane >> 4) * 257 + (cl >> 1) * 64 + (lane & 15) * 4 + (cl & 1) * 2 + h] = pk;
        }

        // B-frags kk=0 issued BEFORE the barrier (stay in flight across it)
        uint4 bf_c[4];
        #pragma unroll
        for (int nt = 0; nt < 4; ++nt)
            bf_c[nt] = *(const uint4*)(bfrag + ((((size_t)ci * 4 + 0) * 4 + nt) * 64 + lane) * 8);

        // LDS-only barrier: lgkmcnt(0) for s_a visibility, NO vmcnt drain
        asm volatile("s_waitcnt lgkmcnt(0)\n\ts_barrier" ::: "memory");

        const uint4* saR = &s_a[P][buf][0];
        #pragma unroll
        for (int kk = 0; kk < 4; ++kk) {
            uint4 bf_n[4];
            if (kk < 3) {
                #pragma unroll
                for (int nt = 0; nt < 4; ++nt)
                    bf_n[nt] = *(const uint4*)(bfrag + ((((size_t)ci * 4 + kk + 1) * 4 + nt) * 64 + lane) * 8);
            }
            short8 af[2];
            #pragma unroll
            for (int m = 0; m < 2; ++m)
                af[m] = __builtin_bit_cast(short8, saR[(2 * h + m) * 257 + kk * 64 + r * 4 + sq]);
            #pragma unroll
            for (int m = 0; m < 2; ++m)
                #pragma unroll
                for (int nt = 0; nt < 4; ++nt)
                    acc[m][nt] = __builtin_amdgcn_mfma_f32_16x16x32_bf16(
                        af[m], __builtin_bit_cast(short8, bf_c[nt]), acc[m][nt], 0, 0, 0);
            #pragma unroll
            for (int nt = 0; nt < 4; ++nt) bf_c[nt] = bf_n[nt];
        }
    }

    // ---- epilogue: store y + BN partial sums.
    // D col=lane&15 (oc), row=quad*4+reg (point within tile).
    // BN: per-(m,nt) lane sums -> shfl-reduce over sq -> LDS cross-wave
    // reduce. Scratch = s_a[0][0] footprint (buf 0): last read of ANY buf-0
    // happened in region ci=6's MFMA, strictly before the region-7 barrier
    // that every wave has passed; region-7 MFMA reads only buf 1 -> disjoint.
    float* yB = y_out + (size_t)b * CC * NN + n0;
    float* sb  = (float*)&s_a[0][0][0];   // [8 row-tiles][64 oc] sums
    float* sb2 = sb + 512;                // [8][64] sumsq
    #pragma unroll
    for (int m = 0; m < 2; ++m)
        #pragma unroll
        for (int nt = 0; nt < 4; ++nt) {
            const int oc = nt * 16 + r;
            const float4 v = make_float4(acc[m][nt][0], acc[m][nt][1],
                                         acc[m][nt][2], acc[m][nt][3]);
            *(float4*)(yB + (size_t)oc * NN + (2 * h + m) * 16 + sq * 4) = v;

            float s  = v.x + v.y + v.z + v.w;
            float ss = v.x * v.x + v.y * v.y + v.z * v.z + v.w * v.w;
            s  += __shfl_xor(s, 16);  s  += __shfl_xor(s, 32);
            ss += __shfl_xor(ss, 16); ss += __shfl_xor(ss, 32);
            if (lane < 16) {                 // lane == r, sq == 0
                sb [(wv * 2 + m) * 64 + oc] = s;
                sb2[(wv * 2 + m) * 64 + oc] = ss;
            }
        }
    __syncthreads();
    if (t < 64) {   // one wave: 64 oc, stride-1 LDS reads, 2 atomics/lane
        float S = 0.f, SS = 0.f;
        #pragma unroll
        for (int q = 0; q < 8; ++q) {
            S  += sb [q * 64 + t];
            SS += sb2[q * 64 + t];
        }
        atomicAdd(&part[b * 64 + t], S);
        atomicAdd(&part[256 + b * 64 + t], SS);
    }
}

__global__ void bn_stats(const float* __restrict__ part,
                         const float* __restrict__ gamma,
                         const float* __restrict__ beta,
                         float* __restrict__ ab)
{
    const int ch = threadIdx.x;
    float S = 0.f, SS = 0.f;
    #pragma unroll
    for (int b = 0; b < BB; ++b) {
        S  += part[b * 64 + ch];
        SS += part[256 + b * 64 + ch];
    }
    const float inv  = 1.0f / (float)(BB * NN);
    const float mean = S * inv;
    const float var  = SS * inv - mean * mean;
    const float a    = gamma[ch] * rsqrtf(var + 1e-5f);
    ab[ch]      = a;
    ab[CC + ch] = beta[ch] - mean * a;
}

__global__ __launch_bounds__(256)
void bn_apply(float* __restrict__ y, const float* __restrict__ ab)
{
    const size_t i = (size_t)blockIdx.x * 256 + threadIdx.x;  // float4 index
    float4* p = (float4*)y;
    float4 v = p[i];
    const int ch = (int)((i * 4) >> 14) & 63;  // (elem / N) % C
    const float a = ab[ch], bb = ab[CC + ch];
    v.x = fmaxf(fmaf(a, v.x, bb), 0.0f);
    v.y = fmaxf(fmaf(a, v.y, bb), 0.0f);
    v.z = fmaxf(fmaf(a, v.z, bb), 0.0f);
    v.w = fmaxf(fmaf(a, v.w, bb), 0.0f);
    p[i] = v;
}

extern "C" void kernel_launch(void* const* d_in, const int* in_sizes, int n_in,
                              void* d_out, int out_size, void* d_ws, size_t ws_size,
                              hipStream_t stream)
{
    const float* xyz        = (const float*)d_in[0];
    const float* points     = (const float*)d_in[1];
    const float* coordinate = (const float*)d_in[2];
    const float* w1         = (const float*)d_in[3];
    const float* b1         = (const float*)d_in[4];
    const float* lin_w      = (const float*)d_in[5];
    // d_in[6] = lin_b: unused — training-mode BN cancels per-channel shifts
    const float* gamma      = (const float*)d_in[7];
    const float* beta       = (const float*)d_in[8];

    float* out = (float*)d_out;

    // workspace: [0,128K) bfrag bf16; then 512 floats partials; then 128 ab
    unsigned short* bfrag = (unsigned short*)d_ws;
    float* part = (float*)d_ws + 32768;
    float* ab   = part + 512;

    const size_t xyz_elems = (size_t)BB * NN * 3;  // output 0 passthrough
    (void)hipMemcpyAsync(out, xyz, xyz_elems * sizeof(float),
                         hipMemcpyDeviceToDevice, stream);

    float* y_out = out + xyz_elems;  // [B][C][N]

    prep_bfrag<<<32, 256, 0, stream>>>(lin_w, bfrag, part);
    fused_main<<<BB * (NN / NTB), 256, 0, stream>>>(
        points, coordinate, w1, b1, bfrag, y_out, part);
    bn_stats<<<1, 64, 0, stream>>>(part, gamma, beta, ab);
    bn_apply<<<(BB * CC * NN) / 4 / 256, 256, 0, stream>>>(y_out, ab);
}